// Round 1
// 195.768 us; speedup vs baseline: 1.0659x; 1.0659x over previous
//
#include <hip/hip_runtime.h>
#include <math.h>

#define D_MODEL 256
#define NHEAD 4
#define HEAD_DIM 64
#define SEQ 4096
#define BATCH 4
#define MROWS (BATCH * SEQ)

typedef __attribute__((ext_vector_type(8))) short short8;
typedef __attribute__((ext_vector_type(4))) short short4v;
typedef __attribute__((ext_vector_type(8))) __bf16 bf16x8;
typedef __attribute__((ext_vector_type(4))) float f32x4;

__device__ inline short f2bf(float f) {  // RNE fp32->bf16
  unsigned u = __float_as_uint(f);
  u += 0x7fffu + ((u >> 16) & 1u);
  return (short)(u >> 16);
}
__device__ inline bf16x8 as_bf8(short8 s) {
  union { short8 s; bf16x8 b; } u;
  u.s = s;
  return u.b;
}
// async global->LDS, 16B per lane; LDS dest = wave-uniform base + lane*16
__device__ __forceinline__ void g2lds16(const void* g, void* l) {
  __builtin_amdgcn_global_load_lds(
      (const __attribute__((address_space(1))) unsigned int*)g,
      (__attribute__((address_space(3))) unsigned int*)l, 16, 0, 0);
}

#define QSCALE 0.1803368801111204f  /* 0.125 * log2(e): exp2-domain scores */

// ---- weight cvt fp32->bf16, row-major with XOR-swizzled 16B groups --------
// element (n,k) -> n*256 + (k>>5)*32 + (((k>>3)&3) ^ (n&3))*8 + (k&7)
__global__ __launch_bounds__(256) void wcvt(const float* __restrict__ s0, const float* __restrict__ s1,
                                            const float* __restrict__ s2, const float* __restrict__ s3,
                                            const float* __restrict__ s4, short* __restrict__ d0,
                                            short* __restrict__ d1, short* __restrict__ d2,
                                            short* __restrict__ d3, short* __restrict__ d4) {
  int mat = blockIdx.x >> 5;
  int e = ((blockIdx.x & 31) * 256 + threadIdx.x) * 8;
  const float* s = mat == 0 ? s0 : mat == 1 ? s1 : mat == 2 ? s2 : mat == 3 ? s3 : s4;
  short* d = mat == 0 ? d0 : mat == 1 ? d1 : mat == 2 ? d2 : mat == 3 ? d3 : d4;
  int n = e >> 8, k0 = e & 255;
  float4 f0 = *(const float4*)(s + n * 256 + k0);
  float4 f1 = *(const float4*)(s + n * 256 + k0 + 4);
  short8 o = {f2bf(f0.x), f2bf(f0.y), f2bf(f0.z), f2bf(f0.w),
              f2bf(f1.x), f2bf(f1.y), f2bf(f1.z), f2bf(f1.w)};
  int chunk = k0 >> 5, g = (k0 >> 3) & 3;
  *(short8*)(d + n * 256 + chunk * 32 + ((g ^ (n & 3)) * 8)) = o;
}

// ---- LayerNorm fp32 -> bf16 swizzled rows (8 rows/block, 32 thr/row) ------
__global__ __launch_bounds__(256) void ln_sw(const float* __restrict__ x,
                                             const float* __restrict__ g,
                                             const float* __restrict__ b,
                                             short* __restrict__ o) {
  int r = threadIdx.x >> 5, c8 = threadIdx.x & 31;
  int row = blockIdx.x * 8 + r;
  const float* xr = x + (size_t)row * D_MODEL + c8 * 8;
  float4 a = *(const float4*)xr;
  float4 c = *(const float4*)(xr + 4);
  float s = a.x + a.y + a.z + a.w + c.x + c.y + c.z + c.w;
#pragma unroll
  for (int off = 16; off > 0; off >>= 1) s += __shfl_xor(s, off);
  float mu = s * (1.0f / D_MODEL);
  float d0 = a.x - mu, d1 = a.y - mu, d2 = a.z - mu, d3 = a.w - mu;
  float d4 = c.x - mu, d5 = c.y - mu, d6 = c.z - mu, d7 = c.w - mu;
  float ss = d0 * d0 + d1 * d1 + d2 * d2 + d3 * d3 + d4 * d4 + d5 * d5 + d6 * d6 + d7 * d7;
#pragma unroll
  for (int off = 16; off > 0; off >>= 1) ss += __shfl_xor(ss, off);
  float rstd = rsqrtf(ss * (1.0f / D_MODEL) + 1e-5f);
  float4 ga = *(const float4*)(g + c8 * 8);
  float4 gc = *(const float4*)(g + c8 * 8 + 4);
  float4 ba = *(const float4*)(b + c8 * 8);
  float4 bc = *(const float4*)(b + c8 * 8 + 4);
  short8 ov = {f2bf(d0 * rstd * ga.x + ba.x), f2bf(d1 * rstd * ga.y + ba.y),
               f2bf(d2 * rstd * ga.z + ba.z), f2bf(d3 * rstd * ga.w + ba.w),
               f2bf(d4 * rstd * gc.x + bc.x), f2bf(d5 * rstd * gc.y + bc.y),
               f2bf(d6 * rstd * gc.z + bc.z), f2bf(d7 * rstd * gc.w + bc.w)};
  int chunk = c8 >> 2, gr = c8 & 3;
  *(short8*)(o + (size_t)row * D_MODEL + chunk * 32 + ((gr ^ (row & 3)) * 8)) = ov;
}

// ---- QKV GEMM: X panel in LDS once, W fragments DIRECT from L2 image ------
// grid (256, 3): 64-row m-tile, y = which in {Q,K,V}. One barrier per block.
__global__ __launch_bounds__(256) void qkv_direct(
    const short* __restrict__ Wqi, const short* __restrict__ Wki,
    const short* __restrict__ Wvi, const short* __restrict__ Xn,
    short* __restrict__ qo, short* __restrict__ kimg, short* __restrict__ vimg) {
  __shared__ __align__(16) short Xs[64 * 256];  // 32 KB
  const int t = threadIdx.x, lane = t & 63, w = t >> 6;
  const int l15 = lane & 15, quad = lane >> 4;
  const int m0 = blockIdx.x * 64;
  const int which = blockIdx.y;
  const short* Wb = which == 0 ? Wqi : which == 1 ? Wki : Wvi;

#pragma unroll
  for (int j = 0; j < 8; j++) {
    int so = __builtin_amdgcn_readfirstlane((w * 8 + j) * 512);
    g2lds16(Xn + (size_t)m0 * D_MODEL + so + lane * 8, &Xs[so]);
  }
  __syncthreads();

  // hoisted fragment bases (all further offsets compile-time)
  const short* xb = &Xs[l15 * 256 + ((quad ^ (l15 & 3)) * 8)];
  const short* wb = Wb + (size_t)(w * 64 + l15) * 256 + ((quad ^ (l15 & 3)) * 8);

  f32x4 acc[4][4];
#pragma unroll
  for (int i = 0; i < 4; i++)
#pragma unroll
    for (int j = 0; j < 4; j++) acc[i][j] = (f32x4){0.f, 0.f, 0.f, 0.f};

#pragma unroll
  for (int kf = 0; kf < 8; kf++) {
    bf16x8 fx[4], fw[4];
#pragma unroll
    for (int i = 0; i < 4; i++) {
      fx[i] = as_bf8(*(const short8*)(xb + i * 4096 + kf * 32));
      fw[i] = as_bf8(*(const short8*)(wb + i * 4096 + kf * 32));
    }
    if (which == 2) {
#pragma unroll
      for (int mt = 0; mt < 4; mt++)
#pragma unroll
        for (int nt = 0; nt < 4; nt++)
          acc[mt][nt] = __builtin_amdgcn_mfma_f32_16x16x32_bf16(fx[mt], fw[nt], acc[mt][nt], 0, 0, 0);
    } else {
#pragma unroll
      for (int mt = 0; mt < 4; mt++)
#pragma unroll
        for (int nt = 0; nt < 4; nt++)
          acc[mt][nt] = __builtin_amdgcn_mfma_f32_16x16x32_bf16(fw[nt], fx[mt], acc[mt][nt], 0, 0, 0);
    }
  }

#pragma unroll
  for (int mt = 0; mt < 4; mt++)
#pragma unroll
    for (int nt = 0; nt < 4; nt++) {
      f32x4 v = acc[mt][nt];
      if (which == 2) {  // VT image: C[m=s][n=feature] (rows via quad*4+r)
        int n = w * 64 + nt * 16 + l15;
        int mr = m0 + mt * 16 + quad * 4;
        int b = mr >> 12, s = mr & 4095, h = n >> 6, d = n & 63;
        size_t off = ((size_t)(b * NHEAD + h) * 64 + (s >> 6)) * 4096 +
                     (size_t)d * 64 + ((((s & 63) >> 3) ^ (d & 7)) * 8) + (s & 7);
        short4v o = {f2bf(v[0]), f2bf(v[1]), f2bf(v[2]), f2bf(v[3])};
        *(short4v*)(vimg + off) = o;
      } else {  // C[n][m]: col = m via l15, row = n via quad*4+r
        int m = m0 + mt * 16 + l15;
        int nb = w * 64 + nt * 16 + quad * 4;
        if (which == 0) {  // Q row-major, exp2-domain scale folded in
          v *= QSCALE;
          short4v o = {f2bf(v[0]), f2bf(v[1]), f2bf(v[2]), f2bf(v[3])};
          *(short4v*)(qo + (size_t)m * D_MODEL + nb) = o;
        } else {  // K image
          int b = m >> 12, s = m & 4095, h = nb >> 6, d = nb & 63;
          size_t off = ((size_t)(b * NHEAD + h) * 64 + (s >> 6)) * 4096 +
                       (size_t)(s & 63) * 64 + (((d >> 3) ^ (s & 7)) * 8) + (d & 7);
          short4v o = {f2bf(v[0]), f2bf(v[1]), f2bf(v[2]), f2bf(v[3])};
          *(short4v*)(kimg + off) = o;
        }
      }
    }
}

// ---- FFN: 32-row tiles, f1 LDS-resident, W direct from L2 images ----------
// grid 512 (2+ blocks/CU), 2 barriers per block.
__global__ __launch_bounds__(256) void ffn_direct(
    const short* __restrict__ w1i, const short* __restrict__ w2i,
    const short* __restrict__ Hsw, const float* __restrict__ bf1,
    const float* __restrict__ bf2, const float* __restrict__ xt,
    float* __restrict__ out) {
  __shared__ __align__(16) short Hs[32 * 256];   // 16 KB (image layout)
  __shared__ __align__(16) short F1s[32 * 264];  // 16.5 KB (padded rows)
  const int t = threadIdx.x, lane = t & 63, w = t >> 6;
  const int l15 = lane & 15, quad = lane >> 4;
  const int m0 = blockIdx.x * 32;

#pragma unroll
  for (int j = 0; j < 4; j++) {
    int so = __builtin_amdgcn_readfirstlane((w * 4 + j) * 512);
    g2lds16(Hsw + (size_t)m0 * D_MODEL + so + lane * 8, &Hs[so]);
  }
  __syncthreads();

  const short* hb = &Hs[l15 * 256 + ((quad ^ (l15 & 3)) * 8)];
  const short* w1b = w1i + (size_t)(w * 64 + l15) * 256 + ((quad ^ (l15 & 3)) * 8);
  const short* w2b = w2i + (size_t)(w * 64 + l15) * 256 + ((quad ^ (l15 & 3)) * 8);

  // ---- GEMM1: C[n1][m] = W1 . h^T ; wave owns 64 n1, all 32 m ----
  f32x4 a1[2][4];
#pragma unroll
  for (int i = 0; i < 2; i++)
#pragma unroll
    for (int j = 0; j < 4; j++) a1[i][j] = (f32x4){0.f, 0.f, 0.f, 0.f};
#pragma unroll
  for (int kf = 0; kf < 8; kf++) {
    bf16x8 fh[2], fw1[4];
#pragma unroll
    for (int i = 0; i < 2; i++) fh[i] = as_bf8(*(const short8*)(hb + i * 4096 + kf * 32));
#pragma unroll
    for (int i = 0; i < 4; i++) fw1[i] = as_bf8(*(const short8*)(w1b + i * 4096 + kf * 32));
#pragma unroll
    for (int mt = 0; mt < 2; mt++)
#pragma unroll
      for (int nt = 0; nt < 4; nt++)
        a1[mt][nt] = __builtin_amdgcn_mfma_f32_16x16x32_bf16(fw1[nt], fh[mt], a1[mt][nt], 0, 0, 0);
  }
  // f1 = relu(D1 + bf1) -> F1s[m][n1]
#pragma unroll
  for (int mt = 0; mt < 2; mt++)
#pragma unroll
    for (int nt = 0; nt < 4; nt++) {
      int n1 = w * 64 + nt * 16 + quad * 4;
      int ml = mt * 16 + l15;
      float4 bv = *(const float4*)(bf1 + n1);
      f32x4 v = a1[mt][nt];
      short4v o = {f2bf(fmaxf(v[0] + bv.x, 0.f)), f2bf(fmaxf(v[1] + bv.y, 0.f)),
                   f2bf(fmaxf(v[2] + bv.z, 0.f)), f2bf(fmaxf(v[3] + bv.w, 0.f))};
      *(short4v*)&F1s[ml * 264 + n1] = o;
    }
  __syncthreads();

  // ---- GEMM2: C[m][n2] = f1 . W2^T ; wave owns 64 n2 ----
  const short* fb = &F1s[l15 * 264 + quad * 8];
  f32x4 a2[2][4];
#pragma unroll
  for (int i = 0; i < 2; i++)
#pragma unroll
    for (int j = 0; j < 4; j++) a2[i][j] = (f32x4){0.f, 0.f, 0.f, 0.f};
#pragma unroll
  for (int kf = 0; kf < 8; kf++) {
    bf16x8 ff[2], fw2[4];
#pragma unroll
    for (int i = 0; i < 2; i++) ff[i] = as_bf8(*(const short8*)(fb + i * 16 * 264 + kf * 32));
#pragma unroll
    for (int i = 0; i < 4; i++) fw2[i] = as_bf8(*(const short8*)(w2b + i * 4096 + kf * 32));
#pragma unroll
    for (int mt = 0; mt < 2; mt++)
#pragma unroll
      for (int nt = 0; nt < 4; nt++)
        a2[mt][nt] = __builtin_amdgcn_mfma_f32_16x16x32_bf16(ff[mt], fw2[nt], a2[mt][nt], 0, 0, 0);
  }
  // out = D2 + bf2 + xt
#pragma unroll
  for (int mt = 0; mt < 2; mt++)
#pragma unroll
    for (int nt = 0; nt < 4; nt++) {
      int n2 = w * 64 + nt * 16 + l15;
      int mg = m0 + mt * 16 + quad * 4;
      float bv = bf2[n2];
      f32x4 v = a2[mt][nt];
#pragma unroll
      for (int r = 0; r < 4; r++) {
        size_t a = (size_t)(mg + r) * D_MODEL + n2;
        out[a] = v[r] + bv + xt[a];
      }
    }
}

// ---- MFMA flash attention v5: software-pipelined staging ------------------
// One q-tile (64 rows) per block, grid (16 bh, 64 tiles), qt = 63-blockIdx.y
// so the biggest blocks dispatch first (dynamic balancing, 3 blocks/CU).
// 2-phase pipeline: V(t+1) staged after end-barrier (flies under QK(t+1)),
// K(t+1) staged after mid-barrier (flies under PV(t)). Same 2 barriers/iter,
// same 50176 B LDS as v4, but no staging load sits serially before compute.
__global__ __launch_bounds__(256) void attn_v5(const short* __restrict__ qb,
                                               const short* __restrict__ kimg,
                                               const short* __restrict__ vimg,
                                               const float* __restrict__ x,
                                               float* __restrict__ xt) {
  __shared__ __align__(16) short Ks[2 * 4096];
  __shared__ __align__(16) short Vs[2 * 4096];
  __shared__ __align__(16) short Pt[4][16 * 136];

  const int t = threadIdx.x, lane = t & 63, w = t >> 6;
  const int quad = lane >> 4, l15 = lane & 15, l7 = lane & 7;
  const int qt = 63 - blockIdx.y;  // big tiles first
  const int bh = blockIdx.x, b = bh >> 2, h = bh & 3;
  const int ldsoff = __builtin_amdgcn_readfirstlane(w * 512);
  const short* kb_bh = kimg + (size_t)bh * 64 * 4096;
  const short* vb_bh = vimg + (size_t)bh * 64 * 4096;

  // hoisted LDS fragment bases (offsets below are compile-time constants)
  const short* kb0 = &Ks[l15 * 64 + ((quad ^ l7) * 8)];
  const short* kb1 = &Ks[l15 * 64 + (((4 + quad) ^ l7) * 8)];
  const short* vb0 = &Vs[l15 * 64 + ((quad ^ l7) * 8)];
  const short* vb1 = &Vs[l15 * 64 + (((4 + quad) ^ l7) * 8)];
  short* pw = &Pt[w][l15 * 136];

  const int q0 = qt * 64;
  const int qrow = q0 + w * 16 + l15;
  const int wq_lo = q0 + w * 16, wq_hi = wq_lo + 15;

  bf16x8 qf0, qf1;
  {
    const short* qp = qb + ((size_t)(b * SEQ + qrow)) * D_MODEL + h * HEAD_DIM + quad * 8;
    qf0 = as_bf8(*(const short8*)qp);
    qf1 = as_bf8(*(const short8*)(qp + 32));
  }
  f32x4 oacc[4];
#pragma unroll
  for (int i = 0; i < 4; i++) oacc[i] = (f32x4){0.f, 0.f, 0.f, 0.f};
  float lrun = 0.f;

  const int niter = (qt + 2) >> 1;

  // prologue: stage K(0) and V(0); single full drain
#pragma unroll
  for (int i = 0; i < 4; i++) {
    g2lds16(kb_bh + i * 2048 + t * 8, &Ks[i * 2048 + ldsoff]);
    g2lds16(vb_bh + i * 2048 + t * 8, &Vs[i * 2048 + ldsoff]);
  }
  __syncthreads();

  for (int it = 0; it < niter; it++) {
    const int j0 = it * 128;

    // ---- QK phase (K(it) resident; V(it) stage may still be in flight) ----
    const bool half1 = (j0 + 64) <= wq_hi;  // wave-uniform
    const int kcmax = half1 ? 8 : 4;
    f32x4 st[8];
#pragma unroll
    for (int kc = 0; kc < 8; kc++) {
      if (kc < kcmax) {
        f32x4 z = (f32x4){0.f, 0.f, 0.f, 0.f};
        bf16x8 kf0 = as_bf8(*(const short8*)(kb0 + (kc & 3) * 1024 + (kc >> 2) * 4096));
        bf16x8 kf1 = as_bf8(*(const short8*)(kb1 + (kc & 3) * 1024 + (kc >> 2) * 4096));
        z = __builtin_amdgcn_mfma_f32_16x16x32_bf16(kf0, qf0, z, 0, 0, 0);
        z = __builtin_amdgcn_mfma_f32_16x16x32_bf16(kf1, qf1, z, 0, 0, 0);
        st[kc] = z;
      }
    }
    // causal mask via sentinel (exp2 -> 0) on diagonal-overlapping iters
    if (j0 + 127 > wq_lo) {
#pragma unroll
      for (int kc = 0; kc < 8; kc++)
        if (kc < kcmax) {
#pragma unroll
          for (int r = 0; r < 4; r++)
            if (j0 + kc * 16 + quad * 4 + r > qrow) st[kc][r] = -1e30f;
        }
    }
    // streaming softmax: p = exp2(s) unnormalized; l accumulated per-lane
#pragma unroll
    for (int kc = 0; kc < 8; kc++) {
      if (kc < kcmax) {
#pragma unroll
        for (int r = 0; r < 4; r++) {
          float p = __builtin_amdgcn_exp2f(st[kc][r]);
          st[kc][r] = p;
          lrun += p;
        }
        unsigned u0 = (__float_as_uint(st[kc][0]) >> 16) | (__float_as_uint(st[kc][1]) & 0xffff0000u);
        unsigned u1 = (__float_as_uint(st[kc][2]) >> 16) | (__float_as_uint(st[kc][3]) & 0xffff0000u);
        uint2 uu = {u0, u1};
        *(uint2*)(pw + kc * 16 + quad * 4) = uu;
      }
    }

    // mid barrier: drains V(it) stage (implicit vmcnt(0)); all waves are done
    // reading Ks, so K(it+1) may be staged into it right after.
    __syncthreads();

    if (it + 1 < niter) {  // stage K(it+1): flies under the PV phase below
      const short* kc_base = kb_bh + (size_t)(2 * (it + 1)) * 4096;
#pragma unroll
      for (int i = 0; i < 4; i++)
        g2lds16(kc_base + i * 2048 + t * 8, &Ks[i * 2048 + ldsoff]);
    }

    // ---- PV phase (V(it) resident, Pt wave-private) ----
    const int fimax = half1 ? 4 : 2;
    bf16x8 pf[4];
#pragma unroll
    for (int fi = 0; fi < 4; fi++)
      if (fi < fimax) pf[fi] = as_bf8(*(const short8*)(pw + fi * 32 + quad * 8));
#pragma unroll
    for (int dt = 0; dt < 4; dt++) {
      f32x4 o = oacc[dt];
#pragma unroll
      for (int fi = 0; fi < 4; fi++) {
        if (fi < fimax) {
          const short* va = (fi & 1) ? vb1 : vb0;
          bf16x8 vf = as_bf8(*(const short8*)(va + dt * 1024 + (fi >> 1) * 4096));
          o = __builtin_amdgcn_mfma_f32_16x16x32_bf16(vf, pf[fi], o, 0, 0, 0);
        }
      }
      oacc[dt] = o;
    }

    // end barrier: drains K(it+1) stage; all waves are done reading Vs,
    // so V(it+1) may be staged into it right after (flies under QK(it+1)).
    __syncthreads();

    if (it + 1 < niter) {
      const short* vc_base = vb_bh + (size_t)(2 * (it + 1)) * 4096;
#pragma unroll
      for (int i = 0; i < 4; i++)
        g2lds16(vc_base + i * 2048 + t * 8, &Vs[i * 2048 + ldsoff]);
    }
  }

  // epilogue: reduce l across the 4 quad groups, then xt = x + O^T / l
  lrun += __shfl_xor(lrun, 16);
  lrun += __shfl_xor(lrun, 32);
  float inv = 1.0f / lrun;
  size_t rowb = ((size_t)(b * SEQ + qrow)) * D_MODEL + h * HEAD_DIM;
#pragma unroll
  for (int dt = 0; dt < 4; dt++) {
    size_t a = rowb + dt * 16 + quad * 4;
    float4 xv = *(const float4*)(x + a);
    float4 o = make_float4(oacc[dt][0] * inv + xv.x, oacc[dt][1] * inv + xv.y,
                           oacc[dt][2] * inv + xv.z, oacc[dt][3] * inv + xv.w);
    *(float4*)(xt + a) = o;
  }
}

// ---------------------------------------------------------------------------
extern "C" void kernel_launch(void* const* d_in, const int* in_sizes, int n_in,
                              void* d_out, int out_size, void* d_ws,
                              size_t ws_size, hipStream_t stream) {
  const float* x = (const float*)d_in[0];
  const float* Wq = (const float*)d_in[1];
  const float* Wk = (const float*)d_in[2];
  const float* Wv = (const float*)d_in[3];
  const float* g1 = (const float*)d_in[4];
  const float* b1 = (const float*)d_in[5];
  const float* g2 = (const float*)d_in[6];
  const float* b2 = (const float*)d_in[7];
  const float* W1 = (const float*)d_in[8];
  const float* bf1 = (const float*)d_in[9];
  const float* W2 = (const float*)d_in[10];
  const float* bf2 = (const float*)d_in[11];
  float* out = (float*)d_out;

  char* ws = (char*)d_ws;
  float* xt = (float*)ws;                       // 16 MB
  short* q_bf = (short*)(ws + (16u << 20));     // 8 MB
  short* kimg = (short*)(ws + (24u << 20));     // 8 MB
  short* vimg = (short*)(ws + (32u << 20));     // 8 MB
  short* xn_sw = (short*)(ws + (40u << 20));    // 8 MB (xn, then h)
  short* wq_i = (short*)(ws + (48u << 20));     // 5 x 128 KB swizzled weights
  short* wk_i = wq_i + 65536;
  short* wv_i = wq_i + 2 * 65536;
  short* w1_i = wq_i + 3 * 65536;
  short* w2_i = wq_i + 4 * 65536;

  dim3 blk(256);
  wcvt<<<160, blk, 0, stream>>>(Wq, Wk, Wv, W1, W2, wq_i, wk_i, wv_i, w1_i, w2_i);
  ln_sw<<<MROWS / 8, blk, 0, stream>>>(x, g1, b1, xn_sw);
  qkv_direct<<<dim3(MROWS / 64, 3), blk, 0, stream>>>(wq_i, wk_i, wv_i, xn_sw,
                                                      q_bf, kimg, vimg);
  attn_v5<<<dim3(16, 64), blk, 0, stream>>>(q_bf, kimg, vimg, x, xt);
  ln_sw<<<MROWS / 8, blk, 0, stream>>>(xt, g2, b2, xn_sw);
  ffn_direct<<<MROWS / 32, blk, 0, stream>>>(w1_i, w2_i, xn_sw, bf1, bf2, xt, out);
}